// Round 8
// baseline (901.367 us; speedup 1.0000x reference)
//
#include <hip/hip_runtime.h>
#include <hip/hip_bf16.h>

typedef __attribute__((ext_vector_type(8))) short bf16x8;
typedef __attribute__((ext_vector_type(4))) short s16x4;
typedef __attribute__((ext_vector_type(4))) float f32x4;

__device__ __forceinline__ short f2bf(float f) {
  union { __hip_bfloat16 h; short s; } u;
  u.h = __float2bfloat16(f);
  return u.s;
}
__device__ __forceinline__ float bf2f(unsigned short s) {
  union { float f; unsigned u; } v; v.u = ((unsigned)s) << 16; return v.f;
}

__device__ __forceinline__ void gld_lds16(const short* g, short* l) {
  __builtin_amdgcn_global_load_lds((const __attribute__((address_space(1))) unsigned*)g,
                                   (__attribute__((address_space(3))) unsigned*)l,
                                   16, 0, 0);
}

#define BARX(N) asm volatile("s_waitcnt vmcnt(" #N ") lgkmcnt(0)\ns_barrier" ::: "memory")
#define BARLG() asm volatile("s_waitcnt lgkmcnt(0)\ns_barrier" ::: "memory")

// W[K][N] fp32 -> bf16 fragment slots: slot s = (kc*(N/16)+f)*64 + lane, lane=(kg,l16)
// content: W[k(kc*32+kg*8+e)][f*16+l16].  PERM: k-col permutation matching H storage:
// k = (kh & ~63) | ((kh&3)<<4) | ((kh>>2)&15)
template <bool PERM>
__global__ void prep_kernel(const float* __restrict__ W, short* __restrict__ out, int K, int N) {
  int s = blockIdx.x * 256 + threadIdx.x;
  int NF = N >> 4;
  int total = (K >> 5) * NF * 64;
  if (s >= total) return;
  int l = s & 63, kcf = s >> 6;
  int kc = kcf / NF, f = kcf - kc * NF;
  int kg = l >> 4, l16 = l & 15;
  bf16x8 o;
#pragma unroll
  for (int e = 0; e < 8; ++e) {
    int kh = kc * 32 + kg * 8 + e;
    int k = PERM ? ((kh & ~63) | ((kh & 3) << 4) | ((kh >> 2) & 15)) : kh;
    o[e] = f2bf(W[(size_t)k * N + f * 16 + l16]);
  }
  *(bf16x8*)(out + (size_t)s * 8) = o;
}

// ---------------- CSR aggregation ----------------
__global__ void count_kernel(const int* __restrict__ dst, int* __restrict__ cnt, int E) {
  int i = blockIdx.x * 256 + threadIdx.x;
  if (i < E) atomicAdd(&cnt[dst[i]], 1);
}

__global__ __launch_bounds__(1024) void scan_kernel(const int* __restrict__ cnt,
                                                    int* __restrict__ off,
                                                    int* __restrict__ cursor, int N) {
  __shared__ int wsum[16];
  const int t = threadIdx.x;
  const int w = t >> 6, l = t & 63;
  int running = 0;
  for (int base = 0; base < N; base += 1024) {
    int i = base + t;
    int v = (i < N) ? cnt[i] : 0;
    int x = v;
#pragma unroll
    for (int d = 1; d < 64; d <<= 1) { int y = __shfl_up(x, d); if (l >= d) x += y; }
    if (l == 63) wsum[w] = x;
    __syncthreads();
    if (w == 0) {
      int s = (l < 16) ? wsum[l] : 0;
#pragma unroll
      for (int d = 1; d < 16; d <<= 1) { int y = __shfl_up(s, d); if (l >= d) s += y; }
      if (l < 16) wsum[l] = s;
    }
    __syncthreads();
    int total = wsum[15];
    int wo = (w > 0) ? wsum[w - 1] : 0;
    int excl = running + wo + x - v;
    if (i < N) { off[i] = excl; cursor[i] = excl; }
    running += total;
    __syncthreads();
  }
  if (t == 0) off[N] = running;
}

__global__ void scatter_kernel(const int* __restrict__ dst, int* __restrict__ cursor,
                               int* __restrict__ eidx, int E) {
  int e = blockIdx.x * 256 + threadIdx.x;
  if (e < E) {
    int p = atomicAdd(&cursor[dst[e]], 1);
    eidx[p] = e;
  }
}

__global__ void agg_kernel(const float* __restrict__ edge_out, const int* __restrict__ eidx,
                           const int* __restrict__ off, float* __restrict__ agg, int N) {
  int n = blockIdx.x * 4 + (threadIdx.x >> 6);
  if (n >= N) return;
  int l = threadIdx.x & 63;
  int beg = off[n], end = off[n + 1];
  float ax = 0.f, ay = 0.f;
  int i = beg;
  for (; i + 4 <= end; i += 4) {
    int e0 = eidx[i], e1 = eidx[i + 1], e2 = eidx[i + 2], e3 = eidx[i + 3];
    float2 v0 = *(const float2*)(edge_out + (size_t)e0 * 128 + l * 2);
    float2 v1 = *(const float2*)(edge_out + (size_t)e1 * 128 + l * 2);
    float2 v2 = *(const float2*)(edge_out + (size_t)e2 * 128 + l * 2);
    float2 v3 = *(const float2*)(edge_out + (size_t)e3 * 128 + l * 2);
    ax += v0.x + v1.x + v2.x + v3.x;
    ay += v0.y + v1.y + v2.y + v3.y;
  }
  for (; i < end; ++i) {
    int e = eidx[i];
    float2 v = *(const float2*)(edge_out + (size_t)e * 128 + l * 2);
    ax += v.x; ay += v.y;
  }
  float inv = 1.0f / fmaxf((float)(end - beg), 1.0f);
  *(float2*)(agg + (size_t)n * 128 + l * 2) = make_float2(ax * inv, ay * inv);
}

// ---------------- precompute [P|Q] = node_emb @ [eW1a | eW1b]  (bf16 out) ----------------
// P/Q row storage: position p holds col c where p = (c&~63)|((c&15)<<2)|((c>>4)&3)
// (= the writeH position convention; readers compute p(c)).
__launch_bounds__(512, 2)
__global__ void pre_kernel(const float* __restrict__ node_emb, const short* __restrict__ wPre,
                           short* __restrict__ P, short* __restrict__ Q, int Nn) {
  extern __shared__ short smem[];
  short* Bs = smem;            // 3 x 8192 shorts (48 KB)
  short* As = smem + 24576;    // 4 x 4096 shorts (32 KB): all 4 K-chunks of A
  const int tid = threadIdx.x;
  const int m0 = blockIdx.x * 128;
  const int w = tid >> 6, lane = tid & 63, l16 = lane & 15, kg = lane >> 4;
  const int wr = w >> 2, wc = w & 3;
  const int grow = tid >> 2, gk = tid & 3;
  const int grc = min(m0 + grow, Nn - 1);
  const int aslot = (grow >> 4) * 64 + gk * 16 + (grow & 15);

  auto stageU = [&](int v) {
    const short* g = wPre + (size_t)v * 8192;
    short* l = Bs + (size_t)(v % 3) * 8192;
    gld_lds16(g + (size_t)tid * 8, l + (size_t)tid * 8);
    gld_lds16(g + (size_t)(512 + tid) * 8, l + (size_t)(512 + tid) * 8);
  };

  float4 ga[4][2];
#pragma unroll
  for (int c = 0; c < 4; ++c) {
    const float* qp = node_emb + (size_t)grc * 128 + c * 32 + gk * 8;
    ga[c][0] = *(const float4*)qp;
    ga[c][1] = *(const float4*)(qp + 4);
  }
  stageU(0); stageU(1);
#pragma unroll
  for (int c = 0; c < 4; ++c) {
    float t[8];
    *(float4*)t = ga[c][0]; *(float4*)(t + 4) = ga[c][1];
    bf16x8 o;
#pragma unroll
    for (int e = 0; e < 8; ++e) o[e] = f2bf(t[e]);
    *(bf16x8*)&As[(size_t)c * 4096 + (size_t)aslot * 8] = o;
  }
  BARX(2);

  f32x4 accP[16], accQ[16];
#pragma unroll
  for (int i = 0; i < 16; ++i) { f32x4 z = {0.f,0.f,0.f,0.f}; accP[i] = z; accQ[i] = z; }

#pragma unroll
  for (int u = 0; u < 8; ++u) {
    if (u + 2 < 8) stageU(u + 2);
    const short* Ap = As + (size_t)(u & 3) * 4096;
    const short* Bp = Bs + (size_t)(u % 3) * 8192;
    bf16x8 a[4], b[4];
#pragma unroll
    for (int rt = 0; rt < 4; ++rt)
      a[rt] = *(const bf16x8*)&Ap[(size_t)((wr * 4 + rt) * 64 + kg * 16 + l16) * 8];
#pragma unroll
    for (int ct = 0; ct < 4; ++ct)
      b[ct] = *(const bf16x8*)&Bp[(size_t)((wc * 4 + ct) * 64 + lane) * 8];
    if (u < 4) {
#pragma unroll
      for (int rt = 0; rt < 4; ++rt)
#pragma unroll
        for (int ct = 0; ct < 4; ++ct)
          accP[rt * 4 + ct] = __builtin_amdgcn_mfma_f32_16x16x32_bf16(a[rt], b[ct], accP[rt * 4 + ct], 0, 0, 0);
    } else {
#pragma unroll
      for (int rt = 0; rt < 4; ++rt)
#pragma unroll
        for (int ct = 0; ct < 4; ++ct)
          accQ[rt * 4 + ct] = __builtin_amdgcn_mfma_f32_16x16x32_bf16(a[rt], b[ct], accQ[rt * 4 + ct], 0, 0, 0);
    }
    if (u + 2 < 8)      { BARX(2); }
    else if (u + 1 < 8) { BARX(0); }
  }

#pragma unroll
  for (int rt = 0; rt < 4; ++rt)
#pragma unroll
    for (int q = 0; q < 4; ++q) {
      int row = wr * 64 + rt * 16 + kg * 4 + q;
      int rg = m0 + row;
      if (rg < Nn) {
        s16x4 vp, vq;
#pragma unroll
        for (int ct = 0; ct < 4; ++ct) {
          vp[ct] = f2bf(accP[rt * 4 + ct][q]);
          vq[ct] = f2bf(accQ[rt * 4 + ct][q]);
        }
        size_t base = (size_t)rg * 256 + wc * 64 + l16 * 4;
        *(s16x4*)&P[base] = vp;
        *(s16x4*)&Q[base] = vq;
      }
    }
}

struct F8 { float4 a, b; };

// ---------------- fused MLP + LN, BM=128, 512 thr, 128 KB LDS ----------------
// Edge: L1 = e @ W1c (K=128, 4 chunks) + Sinit(P[src]+Q[dst]) injected before H1 write.
// Node: L1 = concat(node_emb, agg) @ nW1 (K=256, 8 chunks).
// L1/L2: waves 2(row)x4(col), each 64r x 64c. L3: row-split (w*16 rows, 128 cols).
// H: addr(row, ch) = row*256 + (ch ^ ((row&7)<<3)); position ch holds col
// c = ((ch&3)<<4)|((ch>>2)&15) per 64-block -- matches PERM'd W2/W3 K-order.
template <bool IS_EDGE>
__launch_bounds__(512, 2)
__global__ void mlp_kernel(const float* __restrict__ node_emb, const float* __restrict__ edge_emb,
                           const int* __restrict__ src, const int* __restrict__ dst,
                           const short* __restrict__ wAll,
                           const short* __restrict__ Pbuf, const short* __restrict__ Qbuf,
                           const float* __restrict__ b1, const float* __restrict__ b2,
                           const float* __restrict__ b3,
                           const float* __restrict__ gam, const float* __restrict__ bet,
                           const float* __restrict__ agg,
                           float* __restrict__ out_base, int M) {
  extern __shared__ short smem[];
  short* BsBase = smem;            // 3 x 8192 shorts (48 KB)
  short* AsBase = smem + 24576;    // 2 x 4096 shorts (16 KB)
  short* Hs     = smem + 32768;    // 32768 shorts (64 KB): 128 x 256 (Sinit, then H1/H2)

  const int tid = threadIdx.x;
  const int m0 = blockIdx.x * 128;
  const int w = tid >> 6, lane = tid & 63, l16 = lane & 15, kg = lane >> 4;
  const int wr = w >> 2, wc = w & 3;

  constexpr int NC1 = IS_EDGE ? 4 : 8;

  const int grow = tid >> 2;
  const int gk = tid & 3;
  const int grc = min(m0 + grow, M - 1);
  const int aslot = (grow >> 4) * 64 + gk * 16 + (grow & 15);

  float b1v[4], b2v[4];
#pragma unroll
  for (int ct = 0; ct < 4; ++ct) {
    int col = wc * 64 + ct * 16 + l16;
    b1v[ct] = b1[col];
    b2v[ct] = b2[col];
  }
  float b3v[8], gv[8], bev[8];
#pragma unroll
  for (int f = 0; f < 8; ++f) {
    int col = f * 16 + l16;
    b3v[f] = b3[col]; gv[f] = gam[col]; bev[f] = bet[col];
  }

  f32x4 acc[16];
#pragma unroll
  for (int i = 0; i < 16; ++i) { f32x4 z = {0.f, 0.f, 0.f, 0.f}; acc[i] = z; }

  auto bsbuf = [&](int v) -> short* { return BsBase + (size_t)(v % 3) * 8192; };
  auto stage1024 = [&](int v) {
    const short* g = wAll + (size_t)v * 8192;
    short* l = bsbuf(v);
    gld_lds16(g + (size_t)tid * 8, l + (size_t)tid * 8);
    gld_lds16(g + (size_t)(512 + tid) * 8, l + (size_t)(512 + tid) * 8);
  };

  auto gatherA = [&](int c) -> F8 {
    const float* q;
    if (IS_EDGE) {
      q = edge_emb + (size_t)grc * 128 + c * 32 + gk * 8;
    } else {
      q = ((c < 4) ? node_emb : agg) + (size_t)grc * 128 + (c & 3) * 32 + gk * 8;
    }
    F8 r;
    r.a = *(const float4*)q;
    r.b = *(const float4*)(q + 4);
    return r;
  };
  auto writeA = [&](const F8& p, int buf) {
    float t[8];
    *(float4*)t = p.a; *(float4*)(t + 4) = p.b;
    bf16x8 o;
#pragma unroll
    for (int e = 0; e < 8; ++e) o[e] = f2bf(t[e]);
    *(bf16x8*)&AsBase[(size_t)buf * 4096 + (size_t)aslot * 8] = o;
  };

  auto mfma16 = [&](bf16x8* a, bf16x8* b) {
#pragma unroll
    for (int rt = 0; rt < 4; ++rt)
#pragma unroll
      for (int ct = 0; ct < 4; ++ct)
        acc[rt * 4 + ct] = __builtin_amdgcn_mfma_f32_16x16x32_bf16(a[rt], b[ct], acc[rt * 4 + ct], 0, 0, 0);
  };

  auto compA = [&](int i) {
    const short* Ap = AsBase + (size_t)(i & 1) * 4096;
    const short* Bp = bsbuf(i);
    bf16x8 a[4], b[4];
#pragma unroll
    for (int rt = 0; rt < 4; ++rt)
      a[rt] = *(const bf16x8*)&Ap[(size_t)((wr * 4 + rt) * 64 + kg * 16 + l16) * 8];
#pragma unroll
    for (int ct = 0; ct < 4; ++ct)
      b[ct] = *(const bf16x8*)&Bp[(size_t)((wc * 4 + ct) * 64 + lane) * 8];
    mfma16(a, b);
  };

  auto computeH = [&](int j, const short* Bp) {
    bf16x8 a[4], b[4];
#pragma unroll
    for (int rt = 0; rt < 4; ++rt) {
      int row = wr * 64 + rt * 16 + l16;
      int ch = (j * 32 + kg * 8) ^ ((row & 7) << 3);
      a[rt] = *(const bf16x8*)&Hs[(size_t)row * 256 + ch];
    }
#pragma unroll
    for (int ct = 0; ct < 4; ++ct)
      b[ct] = *(const bf16x8*)&Bp[(size_t)((wc * 4 + ct) * 64 + lane) * 8];
    mfma16(a, b);
  };

  auto writeH = [&](const float* bv) {
#pragma unroll
    for (int rt = 0; rt < 4; ++rt)
#pragma unroll
      for (int q = 0; q < 4; ++q) {
        int row = wr * 64 + rt * 16 + kg * 4 + q;
        s16x4 v;
#pragma unroll
        for (int ct = 0; ct < 4; ++ct)
          v[ct] = f2bf(fmaxf(acc[rt * 4 + ct][q] + bv[ct], 0.f));
        int ch = (wc * 64 + l16 * 4) ^ ((row & 7) << 3);
        *(s16x4*)&Hs[(size_t)row * 256 + ch] = v;
      }
#pragma unroll
    for (int i = 0; i < 16; ++i) { f32x4 z = {0.f, 0.f, 0.f, 0.f}; acc[i] = z; }
  };

  auto computeL3 = [&](int kk, const short* Bp) {
    int row = w * 16 + l16;
    int ch = (kk * 32 + kg * 8) ^ ((row & 7) << 3);
    bf16x8 a = *(const bf16x8*)&Hs[(size_t)row * 256 + ch];
    const short* Bsub = Bp + (size_t)(kk & 1) * 4096;
#pragma unroll
    for (int f = 0; f < 8; ++f) {
      bf16x8 b = *(const bf16x8*)&Bsub[(size_t)(f * 64 + lane) * 8];
      acc[f] = __builtin_amdgcn_mfma_f32_16x16x32_bf16(a, b, acc[f], 0, 0, 0);
    }
  };

  // ---- prologue ----
  F8 h0 = gatherA(0);
  F8 hold = gatherA(1);
  stage1024(0);
  stage1024(1);
  if (IS_EDGE) {
    // Sinit = P[src] + Q[dst] -> Hs, stored at XOR'd positions (one-time)
    const int r2 = tid >> 2;
    const int j4 = tid & 3;
    const int rc2 = min(m0 + r2, M - 1);
    const int sr = src[rc2], dr = dst[rc2];
    const short* Pp = Pbuf + (size_t)sr * 256;
    const short* Qp = Qbuf + (size_t)dr * 256;
#pragma unroll
    for (int g = 0; g < 8; ++g) {
      int pos = j4 * 64 + g * 8;
      bf16x8 pv = *(const bf16x8*)&Pp[pos];
      bf16x8 qv = *(const bf16x8*)&Qp[pos];
      bf16x8 o;
#pragma unroll
      for (int e = 0; e < 8; ++e)
        o[e] = f2bf(bf2f((unsigned short)pv[e]) + bf2f((unsigned short)qv[e]));
      *(bf16x8*)&Hs[(size_t)r2 * 256 + (pos ^ ((r2 & 7) << 3))] = o;
    }
  }
  writeA(h0, 0);
  BARX(2);

  // ---- layer 1 ----
#pragma unroll
  for (int i = 0; i < NC1; ++i) {
    stage1024(i + 2);
    F8 gnew = hold;
    if (i + 2 < NC1) gnew = gatherA(i + 2);
    compA(i);
    if (i + 1 < NC1) writeA(hold, (i + 1) & 1);
    if (i + 2 < NC1) { BARX(4); } else { BARX(2); }
    hold = gnew;
  }
  if (IS_EDGE) {
    // acc += Sinit (scalar reads from Hs; same-wave tile as writeH -> race-free)
#pragma unroll
    for (int rt = 0; rt < 4; ++rt)
#pragma unroll
      for (int q = 0; q < 4; ++q) {
        int row = wr * 64 + rt * 16 + kg * 4 + q;
        int base = row * 256;
        int xo = (row & 7) << 3;
#pragma unroll
        for (int ct = 0; ct < 4; ++ct) {
          int p = wc * 64 + l16 * 4 + ct;
          acc[rt * 4 + ct][q] += bf2f(*(const unsigned short*)&Hs[base + (p ^ xo)]);
        }
      }
  }
  writeH(b1v);
  BARLG();

  // ---- layer 2 (K = 256, N = 256) ----
#pragma unroll
  for (int j = 0; j < 8; ++j) {
    int u = NC1 + j;
    stage1024(u + 2);
    computeH(j, bsbuf(u));
    BARX(2);
  }
  writeH(b2v);
  BARLG();

  // ---- layer 3 (K = 256, N = 128): 4 units x 2 chunks ----
#pragma unroll
  for (int k = 0; k < 4; ++k) {
    int u = NC1 + 8 + k;
    if (k < 2) stage1024(u + 2);
    const short* Bp = bsbuf(u);
    computeL3(2 * k, Bp);
    computeL3(2 * k + 1, Bp);
    if (k == 0 || k == 1) { BARX(2); }
    else if (k == 2)      { BARX(0); }
  }

  // ---- epilogue: bias + LayerNorm + residual ----
#pragma unroll
  for (int q = 0; q < 4; ++q) {
    int rg = m0 + w * 16 + kg * 4 + q;
    float o[8], s1 = 0.f, s2 = 0.f;
#pragma unroll
    for (int f = 0; f < 8; ++f) {
      float x = acc[f][q] + b3v[f];
      o[f] = x; s1 += x; s2 += x * x;
    }
#pragma unroll
    for (int m = 1; m <= 8; m <<= 1) { s1 += __shfl_xor(s1, m); s2 += __shfl_xor(s2, m); }
    float mu = s1 * (1.f / 128.f);
    float var = s2 * (1.f / 128.f) - mu * mu;
    float rs = rsqrtf(var + 1e-5f);
    if (rg < M) {
      const float* resid = (IS_EDGE ? edge_emb : node_emb) + (size_t)rg * 128;
      float* op = out_base + (size_t)rg * 128;
#pragma unroll
      for (int f = 0; f < 8; ++f) {
        int col = f * 16 + l16;
        op[col] = (o[f] - mu) * rs * gv[f] + bev[f] + resid[col];
      }
    }
  }
}

extern "C" void kernel_launch(void* const* d_in, const int* in_sizes, int n_in,
                              void* d_out, int out_size, void* d_ws, size_t ws_size,
                              hipStream_t stream) {
  const float* node_emb = (const float*)d_in[0];
  const float* edge_emb = (const float*)d_in[1];
  const int*   src      = (const int*)d_in[2];
  const int*   dst      = (const int*)d_in[3];
  const float* eW1 = (const float*)d_in[5];
  const float* eb1 = (const float*)d_in[6];
  const float* eW2 = (const float*)d_in[7];
  const float* eb2 = (const float*)d_in[8];
  const float* eW3 = (const float*)d_in[9];
  const float* eb3 = (const float*)d_in[10];
  const float* eg  = (const float*)d_in[11];
  const float* ebt = (const float*)d_in[12];
  const float* nW1 = (const float*)d_in[13];
  const float* nb1 = (const float*)d_in[14];
  const float* nW2 = (const float*)d_in[15];
  const float* nb2 = (const float*)d_in[16];
  const float* nW3 = (const float*)d_in[17];
  const float* nb3 = (const float*)d_in[18];
  const float* ng  = (const float*)d_in[19];
  const float* nbt = (const float*)d_in[20];

  const int Nn = in_sizes[0] / 128;
  const int Ee = in_sizes[2];

  char* ws = (char*)d_ws;
  float* agg  = (float*)ws;  ws += (size_t)Nn * 128 * 4;
  int* cnt_i  = (int*)ws;    ws += (size_t)Nn * 4;
  int* cursor = (int*)ws;    ws += (size_t)Nn * 4;
  int* offv   = (int*)ws;    ws += (size_t)(Nn + 1) * 4;
  int* eidx   = (int*)ws;    ws += (size_t)Ee * 4;
  ws = (char*)(((uintptr_t)ws + 15) & ~(uintptr_t)15);
  short* wPre = (short*)ws;        // 8 units  (eW1a 4 | eW1b 4)  = 65536 shorts
  short* eAll = wPre + 65536;      // 16 units (W1c 4 | W2 8 | W3 4) = 131072
  short* nAll = eAll + 131072;     // 20 units (nW1 8 | nW2 8 | nW3 4) = 163840
  short* Pbuf = nAll + 163840;     // Nn x 256 bf16
  short* Qbuf = Pbuf + (size_t)Nn * 256;

  float* out_node = (float*)d_out;
  float* out_edge = out_node + (size_t)Nn * 128;

  hipMemsetAsync(cnt_i, 0, (size_t)Nn * 4, stream);

  // weight prep
  prep_kernel<false><<<16, 256, 0, stream>>>(eW1, wPre, 128, 256);                  // eW1a
  prep_kernel<false><<<16, 256, 0, stream>>>(eW1 + 128 * 256, wPre + 32768, 128, 256); // eW1b
  prep_kernel<false><<<16, 256, 0, stream>>>(eW1 + 256 * 256, eAll, 128, 256);      // eW1c
  prep_kernel<true><<<32, 256, 0, stream>>>(eW2, eAll + 32768, 256, 256);
  prep_kernel<true><<<16, 256, 0, stream>>>(eW3, eAll + 98304, 256, 128);
  prep_kernel<false><<<32, 256, 0, stream>>>(nW1, nAll, 256, 256);
  prep_kernel<true><<<32, 256, 0, stream>>>(nW2, nAll + 65536, 256, 256);
  prep_kernel<true><<<16, 256, 0, stream>>>(nW3, nAll + 131072, 256, 128);

  // P/Q precompute
  pre_kernel<<<(Nn + 127) / 128, 512, 81920, stream>>>(node_emb, wPre, Pbuf, Qbuf, Nn);

  // CSR
  count_kernel<<<(Ee + 255) / 256, 256, 0, stream>>>(dst, cnt_i, Ee);
  scan_kernel<<<1, 1024, 0, stream>>>(cnt_i, offv, cursor, Nn);
  scatter_kernel<<<(Ee + 255) / 256, 256, 0, stream>>>(dst, cursor, eidx, Ee);

  mlp_kernel<true><<<(Ee + 127) / 128, 512, 131072, stream>>>(
      node_emb, edge_emb, src, dst, eAll, Pbuf, Qbuf,
      eb1, eb2, eb3, eg, ebt, agg, out_edge, Ee);

  agg_kernel<<<(Nn + 3) / 4, 256, 0, stream>>>(out_edge, eidx, offv, agg, Nn);

  mlp_kernel<false><<<(Nn + 127) / 128, 512, 131072, stream>>>(
      node_emb, edge_emb, src, dst, nAll, Pbuf, Qbuf,
      nb1, nb2, nb3, ng, nbt, agg, out_node, Nn);
}